// Round 4
// baseline (624.906 us; speedup 1.0000x reference)
//
#include <hip/hip_runtime.h>

#define S_LEN 512
#define BATCH 64
#define HDIM  1024
#define TWOH  2048
#define EMB   512
#define KDIM  2560      // 2H + EMB
#define VOUT  32000

// ws layout (float offsets)
#define WS_HB    0
#define WS_MS    64
#define WS_CTX   2112
#define WS_RNNT  (WS_CTX + 64*16*2048)       // 2,099,264
#define WS_HIDT  (WS_RNNT + KDIM*64)         // 2,263,104
#define WS_HT    (WS_HIDT + HDIM*64)         // 2,328,640

__device__ __forceinline__ float sigmoidf_(float x) { return 1.f/(1.f+__expf(-x)); }

// K0: hb[b] = hidden[b,:] . energy_W[0:H] + energy_b
__global__ __launch_bounds__(64) void k_hb(const float* __restrict__ hidden,
                                           const float* __restrict__ eW,
                                           const float* __restrict__ eb,
                                           float* __restrict__ ws_hb) {
  int b = blockIdx.x, lane = threadIdx.x;
  float acc = 0.f;
  for (int k = lane; k < HDIM; k += 64) acc += hidden[b*HDIM + k] * eW[k];
#pragma unroll
  for (int st = 32; st >= 1; st >>= 1) acc += __shfl_xor(acc, st, 64);
  if (lane == 0) ws_hb[b] = acc + eb[0];
}

// K1: per (b, chunk of 32 s): partial online-softmax context.
// wave handles 8 s; lane owns d = 4*lane + 256*k, k=0..7.
__global__ __launch_bounds__(256) void k_attn(const float* __restrict__ enc,
                                              const float* __restrict__ eW,
                                              const float* __restrict__ ws_hb,
                                              float* __restrict__ ws_ms,
                                              float* __restrict__ ws_ctx) {
  __shared__ float lds_ms[4][2];
  __shared__ float lds_ctx[4][2048];
  const int lane  = threadIdx.x & 63;
  const int wave  = threadIdx.x >> 6;
  const int chunk = blockIdx.x;   // 0..15
  const int b     = blockIdx.y;   // 0..63

  float4 w4[8];
#pragma unroll
  for (int k = 0; k < 8; ++k)
    w4[k] = *reinterpret_cast<const float4*>(eW + HDIM + 4*lane + 256*k);
  const float hb = ws_hb[b];

  const int s0 = chunk*32 + wave*8;
  const float* base = enc + ((size_t)(s0*BATCH + b))*TWOH + 4*lane;

  // phase A: 8 energies, 64 loads in flight
  float e[8];
#pragma unroll
  for (int i = 0; i < 8; ++i) {
    const float* p = base + (size_t)i*BATCH*TWOH;
    float a0 = 0.f, a1 = 0.f;
#pragma unroll
    for (int k = 0; k < 8; k += 2) {
      float4 v0 = *reinterpret_cast<const float4*>(p + 256*k);
      float4 v1 = *reinterpret_cast<const float4*>(p + 256*(k+1));
      a0 += v0.x*w4[k].x + v0.y*w4[k].y + v0.z*w4[k].z + v0.w*w4[k].w;
      a1 += v1.x*w4[k+1].x + v1.y*w4[k+1].y + v1.z*w4[k+1].z + v1.w*w4[k+1].w;
    }
    e[i] = a0 + a1;
  }
#pragma unroll
  for (int st = 1; st < 64; st <<= 1) {
#pragma unroll
    for (int i = 0; i < 8; ++i) e[i] += __shfl_xor(e[i], st, 64);
  }
  float m = 0.f;  // relu makes all e >= 0
#pragma unroll
  for (int i = 0; i < 8; ++i) { e[i] = fmaxf(e[i] + hb, 0.f); m = fmaxf(m, e[i]); }
  float pr[8], psum = 0.f;
#pragma unroll
  for (int i = 0; i < 8; ++i) { pr[i] = __expf(e[i] - m); psum += pr[i]; }

  // phase B: weighted sum, re-read (L2-hot)
  float4 ctx[8];
#pragma unroll
  for (int k = 0; k < 8; ++k) ctx[k] = make_float4(0.f, 0.f, 0.f, 0.f);
#pragma unroll
  for (int i = 0; i < 8; ++i) {
    const float* p = base + (size_t)i*BATCH*TWOH;
    const float pi = pr[i];
#pragma unroll
    for (int k = 0; k < 8; ++k) {
      float4 v = *reinterpret_cast<const float4*>(p + 256*k);
      ctx[k].x = fmaf(pi, v.x, ctx[k].x);
      ctx[k].y = fmaf(pi, v.y, ctx[k].y);
      ctx[k].z = fmaf(pi, v.z, ctx[k].z);
      ctx[k].w = fmaf(pi, v.w, ctx[k].w);
    }
  }

  // combine 4 waves in LDS
  if (lane == 0) { lds_ms[wave][0] = m; lds_ms[wave][1] = psum; }
  __syncthreads();
  const float M = fmaxf(fmaxf(lds_ms[0][0], lds_ms[1][0]),
                        fmaxf(lds_ms[2][0], lds_ms[3][0]));
  const float wsc = __expf(m - M);
  float ssum = 0.f;
#pragma unroll
  for (int w = 0; w < 4; ++w) ssum += __expf(lds_ms[w][0] - M) * lds_ms[w][1];
#pragma unroll
  for (int k = 0; k < 8; ++k) {
    float4 c = ctx[k];
    c.x *= wsc; c.y *= wsc; c.z *= wsc; c.w *= wsc;
    *reinterpret_cast<float4*>(&lds_ctx[wave][4*lane + 256*k]) = c;
  }
  __syncthreads();
  float* outp = ws_ctx + ((size_t)b*16 + chunk)*TWOH;
  for (int d = threadIdx.x; d < TWOH; d += 256)
    outp[d] = lds_ctx[0][d] + lds_ctx[1][d] + lds_ctx[2][d] + lds_ctx[3][d];
  if (threadIdx.x == 0) {
    ws_ms[((size_t)b*16 + chunk)*2]     = M;
    ws_ms[((size_t)b*16 + chunk)*2 + 1] = ssum;
  }
}

// K2: combine 16 chunk-partials per b; build transposed rnn input + hidden
__global__ __launch_bounds__(256) void k_combine(const float* __restrict__ ws_ms,
                                                 const float* __restrict__ ws_ctx,
                                                 const float* __restrict__ hidden,
                                                 const float* __restrict__ emb_table,
                                                 const int* __restrict__ x,
                                                 float* __restrict__ ws_rnnT,
                                                 float* __restrict__ ws_hidT) {
  const int b = blockIdx.x;
  float mc[16], sc[16];
#pragma unroll
  for (int c = 0; c < 16; ++c) {
    mc[c] = ws_ms[(b*16 + c)*2];
    sc[c] = ws_ms[(b*16 + c)*2 + 1];
  }
  float M = mc[0];
#pragma unroll
  for (int c = 1; c < 16; ++c) M = fmaxf(M, mc[c]);
  float wc[16], Ssum = 0.f;
#pragma unroll
  for (int c = 0; c < 16; ++c) { wc[c] = __expf(mc[c] - M); Ssum += wc[c]*sc[c]; }
  const float inv = 1.f / Ssum;
  for (int d = threadIdx.x; d < TWOH; d += 256) {
    float a = 0.f;
#pragma unroll
    for (int c = 0; c < 16; ++c) a += wc[c] * ws_ctx[((size_t)b*16 + c)*TWOH + d];
    ws_rnnT[(size_t)d*64 + b] = a * inv;
  }
  const int xb = x[b];
  for (int e = threadIdx.x; e < EMB; e += 256)
    ws_rnnT[(size_t)(TWOH + e)*64 + b] = emb_table[(size_t)xb*EMB + e];
  for (int k = threadIdx.x; k < HDIM; k += 256)
    ws_hidT[(size_t)k*64 + b] = hidden[b*HDIM + k];
}

// K3: gates + LSTM. Block handles 4 h-indices x 4 gates; wave = gate, lanes = b.
__global__ __launch_bounds__(256) void k_gates(const float* __restrict__ ws_rnnT,
                                               const float* __restrict__ ws_hidT,
                                               const float* __restrict__ W_ih,
                                               const float* __restrict__ W_hh,
                                               const float* __restrict__ b_ih,
                                               const float* __restrict__ b_hh,
                                               const float* __restrict__ cell,
                                               float* __restrict__ out_h,
                                               float* __restrict__ out_c,
                                               float* __restrict__ ws_hT) {
  __shared__ float lds_in[128*64];
  __shared__ float lds_g[4][4][64];
  const int lane = threadIdx.x & 63;
  const int wave = threadIdx.x >> 6;
  const int h0 = blockIdx.x * 4;

  float acc[4];
  const float* wih[4];
  const float* whh[4];
#pragma unroll
  for (int q = 0; q < 4; ++q) {
    const int j = wave*HDIM + h0 + q;
    acc[q] = b_ih[j] + b_hh[j];
    wih[q] = W_ih + (size_t)j*KDIM;
    whh[q] = W_hh + (size_t)j*HDIM;
  }

#define FMA4(A, WV) A = fmaf(v0, WV.x, A); A = fmaf(v1, WV.y, A); \
                    A = fmaf(v2, WV.z, A); A = fmaf(v3, WV.w, A);

  for (int c = 0; c < 28; ++c) {
    const int k0 = c * 128;
    const float* src = (k0 < KDIM) ? (ws_rnnT + (size_t)k0*64)
                                   : (ws_hidT + (size_t)(k0 - KDIM)*64);
    const float4* s4 = reinterpret_cast<const float4*>(src);
    float4* l4 = reinterpret_cast<float4*>(lds_in);
    for (int i = threadIdx.x; i < 2048; i += 256) l4[i] = s4[i];
    __syncthreads();
    if (k0 < KDIM) {
      for (int kk = 0; kk < 128; kk += 4) {
        const float4 wv0 = *reinterpret_cast<const float4*>(wih[0] + k0 + kk);
        const float4 wv1 = *reinterpret_cast<const float4*>(wih[1] + k0 + kk);
        const float4 wv2 = *reinterpret_cast<const float4*>(wih[2] + k0 + kk);
        const float4 wv3 = *reinterpret_cast<const float4*>(wih[3] + k0 + kk);
        const float v0 = lds_in[(kk+0)*64 + lane];
        const float v1 = lds_in[(kk+1)*64 + lane];
        const float v2 = lds_in[(kk+2)*64 + lane];
        const float v3 = lds_in[(kk+3)*64 + lane];
        FMA4(acc[0], wv0) FMA4(acc[1], wv1) FMA4(acc[2], wv2) FMA4(acc[3], wv3)
      }
    } else {
      const int kh = k0 - KDIM;
      for (int kk = 0; kk < 128; kk += 4) {
        const float4 wv0 = *reinterpret_cast<const float4*>(whh[0] + kh + kk);
        const float4 wv1 = *reinterpret_cast<const float4*>(whh[1] + kh + kk);
        const float4 wv2 = *reinterpret_cast<const float4*>(whh[2] + kh + kk);
        const float4 wv3 = *reinterpret_cast<const float4*>(whh[3] + kh + kk);
        const float v0 = lds_in[(kk+0)*64 + lane];
        const float v1 = lds_in[(kk+1)*64 + lane];
        const float v2 = lds_in[(kk+2)*64 + lane];
        const float v3 = lds_in[(kk+3)*64 + lane];
        FMA4(acc[0], wv0) FMA4(acc[1], wv1) FMA4(acc[2], wv2) FMA4(acc[3], wv3)
      }
    }
    __syncthreads();
  }
#undef FMA4

#pragma unroll
  for (int q = 0; q < 4; ++q) lds_g[wave][q][lane] = acc[q];
  __syncthreads();
  const int hl = wave;
  const int b = lane;
  const float iv = sigmoidf_(lds_g[0][hl][b]);
  const float fv = sigmoidf_(lds_g[1][hl][b]);
  const float gv = tanhf(lds_g[2][hl][b]);
  const float ov = sigmoidf_(lds_g[3][hl][b]);
  const int h = h0 + hl;
  const float cold = cell[b*HDIM + h];
  const float cn = fmaf(fv, cold, iv*gv);
  const float hn = ov * tanhf(cn);
  out_h[b*HDIM + h] = hn;
  out_c[b*HDIM + h] = cn;
  ws_hT[(size_t)h*64 + b] = hn;
}

// K4: preds[b,o] = h_new[b,:] . fc_W[o,:] + fc_b[o].
// v2: 8 rows/wave, 4 waves/block, 1000 blocks -> ~4 waves/SIMD occupancy.
// h staged in LDS 32KB chunks [128k][64b]; weight reads are wave-uniform
// broadcast float4 (latency hidden by occupancy + 8-acc ILP).
__global__ __launch_bounds__(256) void k_fc(const float* __restrict__ ws_hT,
                                            const float* __restrict__ fc_W,
                                            const float* __restrict__ fc_b,
                                            float* __restrict__ preds) {
  __shared__ float lds_h[128*64];   // 32 KB
  const int lane = threadIdx.x & 63;
  const int wave = threadIdx.x >> 6;
  const int ob = (blockIdx.x*4 + wave)*8;   // wave's first output row

  float acc[8];
#pragma unroll
  for (int r = 0; r < 8; ++r) acc[r] = 0.f;
  const float* w0 = fc_W + (size_t)ob*HDIM;

  for (int c = 0; c < 8; ++c) {         // 8 chunks of 128 k
    const int k0 = c*128;
    // stage hT[k0..k0+128][0..64] -> LDS (coalesced float4)
    const float4* s4 = reinterpret_cast<const float4*>(ws_hT + (size_t)k0*64);
    float4* l4 = reinterpret_cast<float4*>(lds_h);
    for (int i = threadIdx.x; i < 2048; i += 256) l4[i] = s4[i];
    __syncthreads();
    for (int kk = 0; kk < 128; kk += 4) {
      const float v0 = lds_h[(kk+0)*64 + lane];
      const float v1 = lds_h[(kk+1)*64 + lane];
      const float v2 = lds_h[(kk+2)*64 + lane];
      const float v3 = lds_h[(kk+3)*64 + lane];
#pragma unroll
      for (int r = 0; r < 8; ++r) {
        const float4 wv = *reinterpret_cast<const float4*>(w0 + (size_t)r*HDIM + k0 + kk);
        acc[r] = fmaf(v0, wv.x, acc[r]);
        acc[r] = fmaf(v1, wv.y, acc[r]);
        acc[r] = fmaf(v2, wv.z, acc[r]);
        acc[r] = fmaf(v3, wv.w, acc[r]);
      }
    }
    __syncthreads();
  }

  float* p = preds + (size_t)lane*VOUT + ob;
#pragma unroll
  for (int r4 = 0; r4 < 8; r4 += 4) {
    float4 st = make_float4(acc[r4]   + fc_b[ob + r4],
                            acc[r4+1] + fc_b[ob + r4+1],
                            acc[r4+2] + fc_b[ob + r4+2],
                            acc[r4+3] + fc_b[ob + r4+3]);
    *reinterpret_cast<float4*>(p + r4) = st;
  }
}

extern "C" void kernel_launch(void* const* d_in, const int* in_sizes, int n_in,
                              void* d_out, int out_size, void* d_ws, size_t ws_size,
                              hipStream_t stream) {
  const int*   x      = (const int*)  d_in[0];
  const float* enc    = (const float*)d_in[1];
  const float* hidden = (const float*)d_in[2];
  const float* cell   = (const float*)d_in[3];
  const float* embt   = (const float*)d_in[4];
  const float* eW     = (const float*)d_in[5];
  const float* eb     = (const float*)d_in[6];
  const float* W_ih   = (const float*)d_in[7];
  const float* W_hh   = (const float*)d_in[8];
  const float* b_ih   = (const float*)d_in[9];
  const float* b_hh   = (const float*)d_in[10];
  const float* fc_W   = (const float*)d_in[11];
  const float* fc_b   = (const float*)d_in[12];

  float* out   = (float*)d_out;
  float* preds = out;                              // 64*32000
  float* out_h = out + (size_t)BATCH*VOUT;         // 64*1024
  float* out_c = out_h + BATCH*HDIM;               // 64*1024
  float* ws    = (float*)d_ws;

  k_hb<<<64, 64, 0, stream>>>(hidden, eW, eb, ws + WS_HB);
  k_attn<<<dim3(16, 64), 256, 0, stream>>>(enc, eW, ws + WS_HB, ws + WS_MS, ws + WS_CTX);
  k_combine<<<64, 256, 0, stream>>>(ws + WS_MS, ws + WS_CTX, hidden, embt, x,
                                    ws + WS_RNNT, ws + WS_HIDT);
  k_gates<<<256, 256, 0, stream>>>(ws + WS_RNNT, ws + WS_HIDT, W_ih, W_hh,
                                   b_ih, b_hh, cell, out_h, out_c, ws + WS_HT);
  k_fc<<<1000, 256, 0, stream>>>(ws + WS_HT, fc_W, fc_b, preds);
}

// Round 5
// 311.525 us; speedup vs baseline: 2.0060x; 2.0060x over previous
//
#include <hip/hip_runtime.h>

#define S_LEN 512
#define BATCH 64
#define HDIM  1024
#define TWOH  2048
#define EMB   512
#define KDIM  2560      // 2H + EMB
#define VOUT  32000

// ws layout (float offsets)
#define WS_HB    0
#define WS_MS    64
#define WS_CTX   2112
#define WS_GP    WS_CTX                      // gate partials [4][4096][64] alias dead ctx region
#define WS_RNNT  (WS_CTX + 64*16*2048)       // 2,099,264
#define WS_HIDT  (WS_RNNT + KDIM*64)         // 2,263,104
#define WS_HT    (WS_HIDT + HDIM*64)         // 2,328,640

__device__ __forceinline__ float sigmoidf_(float x) { return 1.f/(1.f+__expf(-x)); }

// K0: hb[b] = hidden[b,:] . energy_W[0:H] + energy_b
__global__ __launch_bounds__(64) void k_hb(const float* __restrict__ hidden,
                                           const float* __restrict__ eW,
                                           const float* __restrict__ eb,
                                           float* __restrict__ ws_hb) {
  int b = blockIdx.x, lane = threadIdx.x;
  float acc = 0.f;
  for (int k = lane; k < HDIM; k += 64) acc += hidden[b*HDIM + k] * eW[k];
#pragma unroll
  for (int st = 32; st >= 1; st >>= 1) acc += __shfl_xor(acc, st, 64);
  if (lane == 0) ws_hb[b] = acc + eb[0];
}

// K1: per (b, chunk of 32 s): partial online-softmax context.
__global__ __launch_bounds__(256) void k_attn(const float* __restrict__ enc,
                                              const float* __restrict__ eW,
                                              const float* __restrict__ ws_hb,
                                              float* __restrict__ ws_ms,
                                              float* __restrict__ ws_ctx) {
  __shared__ float lds_ms[4][2];
  __shared__ float lds_ctx[4][2048];
  const int lane  = threadIdx.x & 63;
  const int wave  = threadIdx.x >> 6;
  const int chunk = blockIdx.x;   // 0..15
  const int b     = blockIdx.y;   // 0..63

  float4 w4[8];
#pragma unroll
  for (int k = 0; k < 8; ++k)
    w4[k] = *reinterpret_cast<const float4*>(eW + HDIM + 4*lane + 256*k);
  const float hb = ws_hb[b];

  const int s0 = chunk*32 + wave*8;
  const float* base = enc + ((size_t)(s0*BATCH + b))*TWOH + 4*lane;

  float e[8];
#pragma unroll
  for (int i = 0; i < 8; ++i) {
    const float* p = base + (size_t)i*BATCH*TWOH;
    float a0 = 0.f, a1 = 0.f;
#pragma unroll
    for (int k = 0; k < 8; k += 2) {
      float4 v0 = *reinterpret_cast<const float4*>(p + 256*k);
      float4 v1 = *reinterpret_cast<const float4*>(p + 256*(k+1));
      a0 += v0.x*w4[k].x + v0.y*w4[k].y + v0.z*w4[k].z + v0.w*w4[k].w;
      a1 += v1.x*w4[k+1].x + v1.y*w4[k+1].y + v1.z*w4[k+1].z + v1.w*w4[k+1].w;
    }
    e[i] = a0 + a1;
  }
#pragma unroll
  for (int st = 1; st < 64; st <<= 1) {
#pragma unroll
    for (int i = 0; i < 8; ++i) e[i] += __shfl_xor(e[i], st, 64);
  }
  float m = 0.f;
#pragma unroll
  for (int i = 0; i < 8; ++i) { e[i] = fmaxf(e[i] + hb, 0.f); m = fmaxf(m, e[i]); }
  float pr[8], psum = 0.f;
#pragma unroll
  for (int i = 0; i < 8; ++i) { pr[i] = __expf(e[i] - m); psum += pr[i]; }

  float4 ctx[8];
#pragma unroll
  for (int k = 0; k < 8; ++k) ctx[k] = make_float4(0.f, 0.f, 0.f, 0.f);
#pragma unroll
  for (int i = 0; i < 8; ++i) {
    const float* p = base + (size_t)i*BATCH*TWOH;
    const float pi = pr[i];
#pragma unroll
    for (int k = 0; k < 8; ++k) {
      float4 v = *reinterpret_cast<const float4*>(p + 256*k);
      ctx[k].x = fmaf(pi, v.x, ctx[k].x);
      ctx[k].y = fmaf(pi, v.y, ctx[k].y);
      ctx[k].z = fmaf(pi, v.z, ctx[k].z);
      ctx[k].w = fmaf(pi, v.w, ctx[k].w);
    }
  }

  if (lane == 0) { lds_ms[wave][0] = m; lds_ms[wave][1] = psum; }
  __syncthreads();
  const float M = fmaxf(fmaxf(lds_ms[0][0], lds_ms[1][0]),
                        fmaxf(lds_ms[2][0], lds_ms[3][0]));
  const float wsc = __expf(m - M);
  float ssum = 0.f;
#pragma unroll
  for (int w = 0; w < 4; ++w) ssum += __expf(lds_ms[w][0] - M) * lds_ms[w][1];
#pragma unroll
  for (int k = 0; k < 8; ++k) {
    float4 c = ctx[k];
    c.x *= wsc; c.y *= wsc; c.z *= wsc; c.w *= wsc;
    *reinterpret_cast<float4*>(&lds_ctx[wave][4*lane + 256*k]) = c;
  }
  __syncthreads();
  float* outp = ws_ctx + ((size_t)b*16 + chunk)*TWOH;
  for (int d = threadIdx.x; d < TWOH; d += 256)
    outp[d] = lds_ctx[0][d] + lds_ctx[1][d] + lds_ctx[2][d] + lds_ctx[3][d];
  if (threadIdx.x == 0) {
    ws_ms[((size_t)b*16 + chunk)*2]     = M;
    ws_ms[((size_t)b*16 + chunk)*2 + 1] = ssum;
  }
}

// K2: combine 16 chunk-partials per b; build transposed rnn input + hidden.
// NOTE: must finish before k_gates overwrites WS_CTX (stream-ordered, OK).
__global__ __launch_bounds__(256) void k_combine(const float* __restrict__ ws_ms,
                                                 const float* __restrict__ ws_ctx,
                                                 const float* __restrict__ hidden,
                                                 const float* __restrict__ emb_table,
                                                 const int* __restrict__ x,
                                                 float* __restrict__ ws_rnnT,
                                                 float* __restrict__ ws_hidT) {
  const int b = blockIdx.x;
  float mc[16], sc[16];
#pragma unroll
  for (int c = 0; c < 16; ++c) {
    mc[c] = ws_ms[(b*16 + c)*2];
    sc[c] = ws_ms[(b*16 + c)*2 + 1];
  }
  float M = mc[0];
#pragma unroll
  for (int c = 1; c < 16; ++c) M = fmaxf(M, mc[c]);
  float wc[16], Ssum = 0.f;
#pragma unroll
  for (int c = 0; c < 16; ++c) { wc[c] = __expf(mc[c] - M); Ssum += wc[c]*sc[c]; }
  const float inv = 1.f / Ssum;
  for (int d = threadIdx.x; d < TWOH; d += 256) {
    float a = 0.f;
#pragma unroll
    for (int c = 0; c < 16; ++c) a += wc[c] * ws_ctx[((size_t)b*16 + c)*TWOH + d];
    ws_rnnT[(size_t)d*64 + b] = a * inv;
  }
  const int xb = x[b];
  for (int e = threadIdx.x; e < EMB; e += 256)
    ws_rnnT[(size_t)(TWOH + e)*64 + b] = emb_table[(size_t)xb*EMB + e];
  for (int k = threadIdx.x; k < HDIM; k += 256)
    ws_hidT[(size_t)k*64 + b] = hidden[b*HDIM + k];
}

// K3: gate partials. Split-K=4 (896 k each, 7 chunks of 128).
// Block = 32 contiguous gate-rows; wave = 8 rows; lanes = b.
// Weights staged to LDS with per-lane coalesced float4 loads (the round-4 fix).
__global__ __launch_bounds__(256) void k_gates(const float* __restrict__ ws_rnnT,
                                               const float* __restrict__ ws_hidT,
                                               const float* __restrict__ W_ih,
                                               const float* __restrict__ W_hh,
                                               float* __restrict__ ws_gp) {
  __shared__ float  lds_h[128*64];   // 32 KB
  __shared__ float4 lds_w[32*32];    // 16 KB  [row][k/4]
  const int lane = threadIdx.x & 63;
  const int wave = threadIdx.x >> 6;
  const int part = blockIdx.x >> 7;    // 0..3
  const int rg   = blockIdx.x & 127;   // 0..127
  const int j0   = rg * 32;
  const int r0   = wave * 8;

  float acc[8];
#pragma unroll
  for (int r = 0; r < 8; ++r) acc[r] = 0.f;

  for (int c = 0; c < 7; ++c) {
    const int kg = part*896 + c*128;   // chunk never crosses the 2560 boundary
    // stage input chunk [128][64]
    const float* hsrc = (kg < KDIM) ? (ws_rnnT + (size_t)kg*64)
                                    : (ws_hidT + (size_t)(kg - KDIM)*64);
    const float4* s4 = reinterpret_cast<const float4*>(hsrc);
    float4* l4 = reinterpret_cast<float4*>(lds_h);
    for (int i = threadIdx.x; i < 2048; i += 256) l4[i] = s4[i];
    // stage weight tile [32 rows][128 k] coalesced per-lane
    for (int i = threadIdx.x; i < 1024; i += 256) {
      const int r = i >> 5, cc = i & 31;
      const int j = j0 + r;
      const float* wrow = (kg < KDIM) ? (W_ih + (size_t)j*KDIM + kg)
                                      : (W_hh + (size_t)j*HDIM + (kg - KDIM));
      lds_w[i] = *reinterpret_cast<const float4*>(wrow + cc*4);
    }
    __syncthreads();
    for (int kk = 0; kk < 128; kk += 4) {
      const float v0 = lds_h[(kk+0)*64 + lane];
      const float v1 = lds_h[(kk+1)*64 + lane];
      const float v2 = lds_h[(kk+2)*64 + lane];
      const float v3 = lds_h[(kk+3)*64 + lane];
      const int wbase = r0*32 + (kk >> 2);
#pragma unroll
      for (int r = 0; r < 8; ++r) {
        const float4 wv = lds_w[wbase + r*32];
        acc[r] = fmaf(v0, wv.x, acc[r]);
        acc[r] = fmaf(v1, wv.y, acc[r]);
        acc[r] = fmaf(v2, wv.z, acc[r]);
        acc[r] = fmaf(v3, wv.w, acc[r]);
      }
    }
    __syncthreads();
  }
#pragma unroll
  for (int r = 0; r < 8; ++r)
    ws_gp[((size_t)part*4096 + j0 + r0 + r)*64 + lane] = acc[r];
}

// K3b: sum 4 partials + biases, LSTM pointwise.
__global__ __launch_bounds__(256) void k_lstm(const float* __restrict__ ws_gp,
                                              const float* __restrict__ b_ih,
                                              const float* __restrict__ b_hh,
                                              const float* __restrict__ cell,
                                              float* __restrict__ out_h,
                                              float* __restrict__ out_c,
                                              float* __restrict__ ws_hT) {
  const int id = blockIdx.x*256 + threadIdx.x;  // 65536
  const int h = id >> 6, b = id & 63;
  float g[4];
#pragma unroll
  for (int gg = 0; gg < 4; ++gg) {
    const int j = gg*1024 + h;
    float v = b_ih[j] + b_hh[j];
#pragma unroll
    for (int p = 0; p < 4; ++p) v += ws_gp[((size_t)p*4096 + j)*64 + b];
    g[gg] = v;
  }
  const float iv = sigmoidf_(g[0]);
  const float fv = sigmoidf_(g[1]);
  const float gv = tanhf(g[2]);
  const float ov = sigmoidf_(g[3]);
  const float cold = cell[b*HDIM + h];
  const float cn = fmaf(fv, cold, iv*gv);
  const float hn = ov * tanhf(cn);
  out_h[b*HDIM + h] = hn;
  out_c[b*HDIM + h] = cn;
  ws_hT[(size_t)h*64 + b] = hn;
}

// K4 v3: block = 32 output rows, wave = 8 rows, lanes = b.
// Weight tile LDS-staged with coalesced per-lane loads; broadcast ds_read back.
__global__ __launch_bounds__(256) void k_fc(const float* __restrict__ ws_hT,
                                            const float* __restrict__ fc_W,
                                            const float* __restrict__ fc_b,
                                            float* __restrict__ preds) {
  __shared__ float  lds_h[128*64];   // 32 KB
  __shared__ float4 lds_w[32*32];    // 16 KB
  const int lane = threadIdx.x & 63;
  const int wave = threadIdx.x >> 6;
  const int ob = blockIdx.x * 32;
  const int r0 = wave * 8;

  float acc[8];
#pragma unroll
  for (int r = 0; r < 8; ++r) acc[r] = 0.f;

  for (int c = 0; c < 8; ++c) {
    const int k0 = c*128;
    const float4* s4 = reinterpret_cast<const float4*>(ws_hT + (size_t)k0*64);
    float4* l4 = reinterpret_cast<float4*>(lds_h);
    for (int i = threadIdx.x; i < 2048; i += 256) l4[i] = s4[i];
    for (int i = threadIdx.x; i < 1024; i += 256) {
      const int r = i >> 5, cc = i & 31;
      lds_w[i] = *reinterpret_cast<const float4*>(fc_W + (size_t)(ob + r)*HDIM + k0 + cc*4);
    }
    __syncthreads();
    for (int kk = 0; kk < 128; kk += 4) {
      const float v0 = lds_h[(kk+0)*64 + lane];
      const float v1 = lds_h[(kk+1)*64 + lane];
      const float v2 = lds_h[(kk+2)*64 + lane];
      const float v3 = lds_h[(kk+3)*64 + lane];
      const int wbase = r0*32 + (kk >> 2);
#pragma unroll
      for (int r = 0; r < 8; ++r) {
        const float4 wv = lds_w[wbase + r*32];
        acc[r] = fmaf(v0, wv.x, acc[r]);
        acc[r] = fmaf(v1, wv.y, acc[r]);
        acc[r] = fmaf(v2, wv.z, acc[r]);
        acc[r] = fmaf(v3, wv.w, acc[r]);
      }
    }
    __syncthreads();
  }

  const int orow = ob + r0;
  float* p = preds + (size_t)lane*VOUT + orow;
#pragma unroll
  for (int r4 = 0; r4 < 8; r4 += 4) {
    float4 st = make_float4(acc[r4]   + fc_b[orow + r4],
                            acc[r4+1] + fc_b[orow + r4+1],
                            acc[r4+2] + fc_b[orow + r4+2],
                            acc[r4+3] + fc_b[orow + r4+3]);
    *reinterpret_cast<float4*>(p + r4) = st;
  }
}

extern "C" void kernel_launch(void* const* d_in, const int* in_sizes, int n_in,
                              void* d_out, int out_size, void* d_ws, size_t ws_size,
                              hipStream_t stream) {
  const int*   x      = (const int*)  d_in[0];
  const float* enc    = (const float*)d_in[1];
  const float* hidden = (const float*)d_in[2];
  const float* cell   = (const float*)d_in[3];
  const float* embt   = (const float*)d_in[4];
  const float* eW     = (const float*)d_in[5];
  const float* eb     = (const float*)d_in[6];
  const float* W_ih   = (const float*)d_in[7];
  const float* W_hh   = (const float*)d_in[8];
  const float* b_ih   = (const float*)d_in[9];
  const float* b_hh   = (const float*)d_in[10];
  const float* fc_W   = (const float*)d_in[11];
  const float* fc_b   = (const float*)d_in[12];

  float* out   = (float*)d_out;
  float* preds = out;                              // 64*32000
  float* out_h = out + (size_t)BATCH*VOUT;         // 64*1024
  float* out_c = out_h + BATCH*HDIM;               // 64*1024
  float* ws    = (float*)d_ws;

  k_hb<<<64, 64, 0, stream>>>(hidden, eW, eb, ws + WS_HB);
  k_attn<<<dim3(16, 64), 256, 0, stream>>>(enc, eW, ws + WS_HB, ws + WS_MS, ws + WS_CTX);
  k_combine<<<64, 256, 0, stream>>>(ws + WS_MS, ws + WS_CTX, hidden, embt, x,
                                    ws + WS_RNNT, ws + WS_HIDT);
  k_gates<<<512, 256, 0, stream>>>(ws + WS_RNNT, ws + WS_HIDT, W_ih, W_hh, ws + WS_GP);
  k_lstm<<<256, 256, 0, stream>>>(ws + WS_GP, b_ih, b_hh, cell, out_h, out_c, ws + WS_HT);
  k_fc<<<1000, 256, 0, stream>>>(ws + WS_HT, fc_W, fc_b, preds);
}

// Round 6
// 279.020 us; speedup vs baseline: 2.2396x; 1.1165x over previous
//
#include <hip/hip_runtime.h>

#define S_LEN 512
#define BATCH 64
#define HDIM  1024
#define TWOH  2048
#define EMB   512
#define KDIM  2560      // 2H + EMB
#define VOUT  32000

// ws layout (float offsets)
#define WS_HB    0
#define WS_MS    64
#define WS_CTX   2112
#define WS_GP    WS_CTX                      // gate partials [4][4096][64] alias dead ctx region
#define WS_RNNT  (WS_CTX + 64*16*2048)       // 2,099,264
#define WS_HIDT  (WS_RNNT + KDIM*64)         // 2,263,104
#define WS_HT    (WS_HIDT + HDIM*64)         // 2,328,640

__device__ __forceinline__ float sigmoidf_(float x) { return 1.f/(1.f+__expf(-x)); }

// K0: hb[b] = hidden[b,:] . energy_W[0:H] + energy_b
__global__ __launch_bounds__(64) void k_hb(const float* __restrict__ hidden,
                                           const float* __restrict__ eW,
                                           const float* __restrict__ eb,
                                           float* __restrict__ ws_hb) {
  int b = blockIdx.x, lane = threadIdx.x;
  float acc = 0.f;
  for (int k = lane; k < HDIM; k += 64) acc += hidden[b*HDIM + k] * eW[k];
#pragma unroll
  for (int st = 32; st >= 1; st >>= 1) acc += __shfl_xor(acc, st, 64);
  if (lane == 0) ws_hb[b] = acc + eb[0];
}

// K1 v2: single-pass online-softmax context. Wave = 8 s-rows processed in
// 4 pairs; V stays in the registers that computed the energy -> no re-read.
__global__ __launch_bounds__(256) void k_attn(const float* __restrict__ enc,
                                              const float* __restrict__ eW,
                                              const float* __restrict__ ws_hb,
                                              float* __restrict__ ws_ms,
                                              float* __restrict__ ws_ctx) {
  __shared__ float lds_ms[4][2];
  __shared__ float lds_ctx[4][2048];
  const int lane  = threadIdx.x & 63;
  const int wave  = threadIdx.x >> 6;
  const int chunk = blockIdx.x;   // 0..15
  const int b     = blockIdx.y;   // 0..63

  float4 w4[8];
#pragma unroll
  for (int k = 0; k < 8; ++k)
    w4[k] = *reinterpret_cast<const float4*>(eW + HDIM + 4*lane + 256*k);
  const float hb = ws_hb[b];

  const int s0 = chunk*32 + wave*8;
  const float* base = enc + ((size_t)(s0*BATCH + b))*TWOH + 4*lane;

  float m = 0.f, ssum = 0.f;          // relu => energies >= 0, so m=0 is a valid floor
  float4 ctx[8];
#pragma unroll
  for (int k = 0; k < 8; ++k) ctx[k] = make_float4(0.f, 0.f, 0.f, 0.f);

  for (int ip = 0; ip < 4; ++ip) {
    const float* p0 = base + (size_t)(2*ip)*BATCH*TWOH;
    const float* p1 = p0 + (size_t)BATCH*TWOH;
    float4 v0[8], v1[8];
#pragma unroll
    for (int k = 0; k < 8; ++k) {
      v0[k] = *reinterpret_cast<const float4*>(p0 + 256*k);
      v1[k] = *reinterpret_cast<const float4*>(p1 + 256*k);
    }
    float a0 = 0.f, a1 = 0.f;
#pragma unroll
    for (int k = 0; k < 8; ++k) {
      a0 += v0[k].x*w4[k].x + v0[k].y*w4[k].y + v0[k].z*w4[k].z + v0[k].w*w4[k].w;
      a1 += v1[k].x*w4[k].x + v1[k].y*w4[k].y + v1[k].z*w4[k].z + v1[k].w*w4[k].w;
    }
#pragma unroll
    for (int st = 1; st < 64; st <<= 1) {
      a0 += __shfl_xor(a0, st, 64);
      a1 += __shfl_xor(a1, st, 64);
    }
    const float e0 = fmaxf(a0 + hb, 0.f);
    const float e1 = fmaxf(a1 + hb, 0.f);
    const float mnew = fmaxf(m, fmaxf(e0, e1));
    const float sc  = __expf(m - mnew);
    const float pw0 = __expf(e0 - mnew);
    const float pw1 = __expf(e1 - mnew);
    ssum = fmaf(ssum, sc, pw0 + pw1);
#pragma unroll
    for (int k = 0; k < 8; ++k) {
      ctx[k].x = fmaf(pw1, v1[k].x, fmaf(pw0, v0[k].x, ctx[k].x*sc));
      ctx[k].y = fmaf(pw1, v1[k].y, fmaf(pw0, v0[k].y, ctx[k].y*sc));
      ctx[k].z = fmaf(pw1, v1[k].z, fmaf(pw0, v0[k].z, ctx[k].z*sc));
      ctx[k].w = fmaf(pw1, v1[k].w, fmaf(pw0, v0[k].w, ctx[k].w*sc));
    }
    m = mnew;
  }

  // combine 4 waves in LDS
  if (lane == 0) { lds_ms[wave][0] = m; lds_ms[wave][1] = ssum; }
  __syncthreads();
  const float M = fmaxf(fmaxf(lds_ms[0][0], lds_ms[1][0]),
                        fmaxf(lds_ms[2][0], lds_ms[3][0]));
  const float wsc = __expf(m - M);
  float ssum_c = 0.f;
#pragma unroll
  for (int w = 0; w < 4; ++w) ssum_c += __expf(lds_ms[w][0] - M) * lds_ms[w][1];
#pragma unroll
  for (int k = 0; k < 8; ++k) {
    float4 c = ctx[k];
    c.x *= wsc; c.y *= wsc; c.z *= wsc; c.w *= wsc;
    *reinterpret_cast<float4*>(&lds_ctx[wave][4*lane + 256*k]) = c;
  }
  __syncthreads();
  float* outp = ws_ctx + ((size_t)b*16 + chunk)*TWOH;
  for (int d = threadIdx.x; d < TWOH; d += 256)
    outp[d] = lds_ctx[0][d] + lds_ctx[1][d] + lds_ctx[2][d] + lds_ctx[3][d];
  if (threadIdx.x == 0) {
    ws_ms[((size_t)b*16 + chunk)*2]     = M;
    ws_ms[((size_t)b*16 + chunk)*2 + 1] = ssum_c;
  }
}

// K2: combine 16 chunk-partials per b; build transposed rnn input + hidden.
__global__ __launch_bounds__(256) void k_combine(const float* __restrict__ ws_ms,
                                                 const float* __restrict__ ws_ctx,
                                                 const float* __restrict__ hidden,
                                                 const float* __restrict__ emb_table,
                                                 const int* __restrict__ x,
                                                 float* __restrict__ ws_rnnT,
                                                 float* __restrict__ ws_hidT) {
  const int b = blockIdx.x;
  float mc[16], sc[16];
#pragma unroll
  for (int c = 0; c < 16; ++c) {
    mc[c] = ws_ms[(b*16 + c)*2];
    sc[c] = ws_ms[(b*16 + c)*2 + 1];
  }
  float M = mc[0];
#pragma unroll
  for (int c = 1; c < 16; ++c) M = fmaxf(M, mc[c]);
  float wc[16], Ssum = 0.f;
#pragma unroll
  for (int c = 0; c < 16; ++c) { wc[c] = __expf(mc[c] - M); Ssum += wc[c]*sc[c]; }
  const float inv = 1.f / Ssum;
  for (int d = threadIdx.x; d < TWOH; d += 256) {
    float a = 0.f;
#pragma unroll
    for (int c = 0; c < 16; ++c) a += wc[c] * ws_ctx[((size_t)b*16 + c)*TWOH + d];
    ws_rnnT[(size_t)d*64 + b] = a * inv;
  }
  const int xb = x[b];
  for (int e = threadIdx.x; e < EMB; e += 256)
    ws_rnnT[(size_t)(TWOH + e)*64 + b] = emb_table[(size_t)xb*EMB + e];
  for (int k = threadIdx.x; k < HDIM; k += 256)
    ws_hidT[(size_t)k*64 + b] = hidden[b*HDIM + k];
}

// K3: gate partials. Split-K=4 (896 k each, 7 chunks of 128).
__global__ __launch_bounds__(256) void k_gates(const float* __restrict__ ws_rnnT,
                                               const float* __restrict__ ws_hidT,
                                               const float* __restrict__ W_ih,
                                               const float* __restrict__ W_hh,
                                               float* __restrict__ ws_gp) {
  __shared__ float  lds_h[128*64];   // 32 KB
  __shared__ float4 lds_w[32*32];    // 16 KB  [row][k/4]
  const int lane = threadIdx.x & 63;
  const int wave = threadIdx.x >> 6;
  const int part = blockIdx.x >> 7;    // 0..3
  const int rg   = blockIdx.x & 127;   // 0..127
  const int j0   = rg * 32;
  const int r0   = wave * 8;

  float acc[8];
#pragma unroll
  for (int r = 0; r < 8; ++r) acc[r] = 0.f;

  for (int c = 0; c < 7; ++c) {
    const int kg = part*896 + c*128;
    const float* hsrc = (kg < KDIM) ? (ws_rnnT + (size_t)kg*64)
                                    : (ws_hidT + (size_t)(kg - KDIM)*64);
    const float4* s4 = reinterpret_cast<const float4*>(hsrc);
    float4* l4 = reinterpret_cast<float4*>(lds_h);
    for (int i = threadIdx.x; i < 2048; i += 256) l4[i] = s4[i];
    for (int i = threadIdx.x; i < 1024; i += 256) {
      const int r = i >> 5, cc = i & 31;
      const int j = j0 + r;
      const float* wrow = (kg < KDIM) ? (W_ih + (size_t)j*KDIM + kg)
                                      : (W_hh + (size_t)j*HDIM + (kg - KDIM));
      lds_w[i] = *reinterpret_cast<const float4*>(wrow + cc*4);
    }
    __syncthreads();
    for (int kk = 0; kk < 128; kk += 4) {
      const float v0 = lds_h[(kk+0)*64 + lane];
      const float v1 = lds_h[(kk+1)*64 + lane];
      const float v2 = lds_h[(kk+2)*64 + lane];
      const float v3 = lds_h[(kk+3)*64 + lane];
      const int wbase = r0*32 + (kk >> 2);
#pragma unroll
      for (int r = 0; r < 8; ++r) {
        const float4 wv = lds_w[wbase + r*32];
        acc[r] = fmaf(v0, wv.x, acc[r]);
        acc[r] = fmaf(v1, wv.y, acc[r]);
        acc[r] = fmaf(v2, wv.z, acc[r]);
        acc[r] = fmaf(v3, wv.w, acc[r]);
      }
    }
    __syncthreads();
  }
#pragma unroll
  for (int r = 0; r < 8; ++r)
    ws_gp[((size_t)part*4096 + j0 + r0 + r)*64 + lane] = acc[r];
}

// K3b: sum 4 partials + biases, LSTM pointwise.
__global__ __launch_bounds__(256) void k_lstm(const float* __restrict__ ws_gp,
                                              const float* __restrict__ b_ih,
                                              const float* __restrict__ b_hh,
                                              const float* __restrict__ cell,
                                              float* __restrict__ out_h,
                                              float* __restrict__ out_c,
                                              float* __restrict__ ws_hT) {
  const int id = blockIdx.x*256 + threadIdx.x;  // 65536
  const int h = id >> 6, b = id & 63;
  float g[4];
#pragma unroll
  for (int gg = 0; gg < 4; ++gg) {
    const int j = gg*1024 + h;
    float v = b_ih[j] + b_hh[j];
#pragma unroll
    for (int p = 0; p < 4; ++p) v += ws_gp[((size_t)p*4096 + j)*64 + b];
    g[gg] = v;
  }
  const float iv = sigmoidf_(g[0]);
  const float fv = sigmoidf_(g[1]);
  const float gv = tanhf(g[2]);
  const float ov = sigmoidf_(g[3]);
  const float cold = cell[b*HDIM + h];
  const float cn = fmaf(fv, cold, iv*gv);
  const float hn = ov * tanhf(cn);
  out_h[b*HDIM + h] = hn;
  out_c[b*HDIM + h] = cn;
  ws_hT[(size_t)h*64 + b] = hn;
}

// K4: block = 32 output rows, wave = 8 rows, lanes = b.
__global__ __launch_bounds__(256) void k_fc(const float* __restrict__ ws_hT,
                                            const float* __restrict__ fc_W,
                                            const float* __restrict__ fc_b,
                                            float* __restrict__ preds) {
  __shared__ float  lds_h[128*64];   // 32 KB
  __shared__ float4 lds_w[32*32];    // 16 KB
  const int lane = threadIdx.x & 63;
  const int wave = threadIdx.x >> 6;
  const int ob = blockIdx.x * 32;
  const int r0 = wave * 8;

  float acc[8];
#pragma unroll
  for (int r = 0; r < 8; ++r) acc[r] = 0.f;

  for (int c = 0; c < 8; ++c) {
    const int k0 = c*128;
    const float4* s4 = reinterpret_cast<const float4*>(ws_hT + (size_t)k0*64);
    float4* l4 = reinterpret_cast<float4*>(lds_h);
    for (int i = threadIdx.x; i < 2048; i += 256) l4[i] = s4[i];
    for (int i = threadIdx.x; i < 1024; i += 256) {
      const int r = i >> 5, cc = i & 31;
      lds_w[i] = *reinterpret_cast<const float4*>(fc_W + (size_t)(ob + r)*HDIM + k0 + cc*4);
    }
    __syncthreads();
    for (int kk = 0; kk < 128; kk += 4) {
      const float v0 = lds_h[(kk+0)*64 + lane];
      const float v1 = lds_h[(kk+1)*64 + lane];
      const float v2 = lds_h[(kk+2)*64 + lane];
      const float v3 = lds_h[(kk+3)*64 + lane];
      const int wbase = r0*32 + (kk >> 2);
#pragma unroll
      for (int r = 0; r < 8; ++r) {
        const float4 wv = lds_w[wbase + r*32];
        acc[r] = fmaf(v0, wv.x, acc[r]);
        acc[r] = fmaf(v1, wv.y, acc[r]);
        acc[r] = fmaf(v2, wv.z, acc[r]);
        acc[r] = fmaf(v3, wv.w, acc[r]);
      }
    }
    __syncthreads();
  }

  const int orow = ob + r0;
  float* p = preds + (size_t)lane*VOUT + orow;
#pragma unroll
  for (int r4 = 0; r4 < 8; r4 += 4) {
    float4 st = make_float4(acc[r4]   + fc_b[orow + r4],
                            acc[r4+1] + fc_b[orow + r4+1],
                            acc[r4+2] + fc_b[orow + r4+2],
                            acc[r4+3] + fc_b[orow + r4+3]);
    *reinterpret_cast<float4*>(p + r4) = st;
  }
}

extern "C" void kernel_launch(void* const* d_in, const int* in_sizes, int n_in,
                              void* d_out, int out_size, void* d_ws, size_t ws_size,
                              hipStream_t stream) {
  const int*   x      = (const int*)  d_in[0];
  const float* enc    = (const float*)d_in[1];
  const float* hidden = (const float*)d_in[2];
  const float* cell   = (const float*)d_in[3];
  const float* embt   = (const float*)d_in[4];
  const float* eW     = (const float*)d_in[5];
  const float* eb     = (const float*)d_in[6];
  const float* W_ih   = (const float*)d_in[7];
  const float* W_hh   = (const float*)d_in[8];
  const float* b_ih   = (const float*)d_in[9];
  const float* b_hh   = (const float*)d_in[10];
  const float* fc_W   = (const float*)d_in[11];
  const float* fc_b   = (const float*)d_in[12];

  float* out   = (float*)d_out;
  float* preds = out;                              // 64*32000
  float* out_h = out + (size_t)BATCH*VOUT;         // 64*1024
  float* out_c = out_h + BATCH*HDIM;               // 64*1024
  float* ws    = (float*)d_ws;

  k_hb<<<64, 64, 0, stream>>>(hidden, eW, eb, ws + WS_HB);
  k_attn<<<dim3(16, 64), 256, 0, stream>>>(enc, eW, ws + WS_HB, ws + WS_MS, ws + WS_CTX);
  k_combine<<<64, 256, 0, stream>>>(ws + WS_MS, ws + WS_CTX, hidden, embt, x,
                                    ws + WS_RNNT, ws + WS_HIDT);
  k_gates<<<512, 256, 0, stream>>>(ws + WS_RNNT, ws + WS_HIDT, W_ih, W_hh, ws + WS_GP);
  k_lstm<<<256, 256, 0, stream>>>(ws + WS_GP, b_ih, b_hh, cell, out_h, out_c, ws + WS_HT);
  k_fc<<<1000, 256, 0, stream>>>(ws + WS_HT, fc_W, fc_b, preds);
}

// Round 7
// 264.903 us; speedup vs baseline: 2.3590x; 1.0533x over previous
//
#include <hip/hip_runtime.h>

#define S_LEN 512
#define BATCH 64
#define HDIM  1024
#define TWOH  2048
#define EMB   512
#define KDIM  2560      // 2H + EMB
#define VOUT  32000

// ws layout (float offsets)
#define WS_HB    0
#define WS_MS    64
#define WS_CTX   2112
#define WS_GP    WS_CTX                      // gate partials [4][4096][64] alias dead ctx region
#define WS_RNNT  (WS_CTX + 64*16*2048)       // 2,099,264
#define WS_HIDT  (WS_RNNT + KDIM*64)         // 2,263,104
#define WS_HT    (WS_HIDT + HDIM*64)         // 2,328,640

__device__ __forceinline__ float sigmoidf_(float x) { return 1.f/(1.f+__expf(-x)); }

// K1 v3: single-pass online-softmax context, row-pipelined (prefetch row i+1
// while computing row i), defer-rescale, hb computed inline (k_hb removed).
__global__ __launch_bounds__(256) void k_attn(const float* __restrict__ enc,
                                              const float* __restrict__ eW,
                                              const float* __restrict__ eb,
                                              const float* __restrict__ hidden,
                                              float* __restrict__ ws_ms,
                                              float* __restrict__ ws_ctx) {
  __shared__ float lds_ms[4][2];
  __shared__ float lds_ctx[4][2048];
  const int lane  = threadIdx.x & 63;
  const int wave  = threadIdx.x >> 6;
  const int chunk = blockIdx.x;   // 0..15
  const int b     = blockIdx.y;   // 0..63

  // hb = hidden[b,:] . eW[0:H] + eb  (each wave redundantly; 16 iters)
  float hba = 0.f;
  for (int k = lane; k < HDIM; k += 64) hba += hidden[b*HDIM + k] * eW[k];
#pragma unroll
  for (int st = 32; st >= 1; st >>= 1) hba += __shfl_xor(hba, st, 64);
  const float hb = hba + eb[0];

  float4 w4[8];
#pragma unroll
  for (int k = 0; k < 8; ++k)
    w4[k] = *reinterpret_cast<const float4*>(eW + HDIM + 4*lane + 256*k);

  const int s0 = chunk*32 + wave*8;
  const float* base = enc + ((size_t)(s0*BATCH + b))*TWOH + 4*lane;

  float m = 0.f, ssum = 0.f;      // relu => e >= 0
  float4 ctx[8];
#pragma unroll
  for (int k = 0; k < 8; ++k) ctx[k] = make_float4(0.f, 0.f, 0.f, 0.f);

  float4 va[8], vb[8];
#pragma unroll
  for (int k = 0; k < 8; ++k) va[k] = *reinterpret_cast<const float4*>(base + 256*k);

#define ATTN_STEP(VCUR, VNXT, I)                                              \
  {                                                                           \
    if ((I) < 7) {                                                            \
      const float* pn = base + (size_t)((I)+1)*BATCH*TWOH;                    \
      _Pragma("unroll")                                                       \
      for (int k = 0; k < 8; ++k)                                             \
        VNXT[k] = *reinterpret_cast<const float4*>(pn + 256*k);               \
    }                                                                         \
    float a = 0.f;                                                            \
    _Pragma("unroll")                                                         \
    for (int k = 0; k < 8; ++k)                                               \
      a += VCUR[k].x*w4[k].x + VCUR[k].y*w4[k].y +                            \
           VCUR[k].z*w4[k].z + VCUR[k].w*w4[k].w;                             \
    _Pragma("unroll")                                                         \
    for (int st = 1; st < 64; st <<= 1) a += __shfl_xor(a, st, 64);           \
    const float e = fmaxf(a + hb, 0.f);                                       \
    if (e > m) {                                                              \
      const float sc = __expf(m - e);                                         \
      ssum = ssum*sc + 1.f;                                                   \
      _Pragma("unroll")                                                       \
      for (int k = 0; k < 8; ++k) {                                           \
        ctx[k].x = fmaf(ctx[k].x, sc, VCUR[k].x);                             \
        ctx[k].y = fmaf(ctx[k].y, sc, VCUR[k].y);                             \
        ctx[k].z = fmaf(ctx[k].z, sc, VCUR[k].z);                             \
        ctx[k].w = fmaf(ctx[k].w, sc, VCUR[k].w);                             \
      }                                                                       \
      m = e;                                                                  \
    } else {                                                                  \
      const float pw = __expf(e - m);                                         \
      ssum += pw;                                                             \
      _Pragma("unroll")                                                       \
      for (int k = 0; k < 8; ++k) {                                           \
        ctx[k].x = fmaf(pw, VCUR[k].x, ctx[k].x);                             \
        ctx[k].y = fmaf(pw, VCUR[k].y, ctx[k].y);                             \
        ctx[k].z = fmaf(pw, VCUR[k].z, ctx[k].z);                             \
        ctx[k].w = fmaf(pw, VCUR[k].w, ctx[k].w);                             \
      }                                                                       \
    }                                                                         \
  }

  ATTN_STEP(va, vb, 0)
  ATTN_STEP(vb, va, 1)
  ATTN_STEP(va, vb, 2)
  ATTN_STEP(vb, va, 3)
  ATTN_STEP(va, vb, 4)
  ATTN_STEP(vb, va, 5)
  ATTN_STEP(va, vb, 6)
  ATTN_STEP(vb, va, 7)
#undef ATTN_STEP

  // combine 4 waves in LDS
  if (lane == 0) { lds_ms[wave][0] = m; lds_ms[wave][1] = ssum; }
  __syncthreads();
  const float M = fmaxf(fmaxf(lds_ms[0][0], lds_ms[1][0]),
                        fmaxf(lds_ms[2][0], lds_ms[3][0]));
  const float wsc = __expf(m - M);
  float ssum_c = 0.f;
#pragma unroll
  for (int w = 0; w < 4; ++w) ssum_c += __expf(lds_ms[w][0] - M) * lds_ms[w][1];
#pragma unroll
  for (int k = 0; k < 8; ++k) {
    float4 c = ctx[k];
    c.x *= wsc; c.y *= wsc; c.z *= wsc; c.w *= wsc;
    *reinterpret_cast<float4*>(&lds_ctx[wave][4*lane + 256*k]) = c;
  }
  __syncthreads();
  float* outp = ws_ctx + ((size_t)b*16 + chunk)*TWOH;
  for (int d = threadIdx.x; d < TWOH; d += 256)
    outp[d] = lds_ctx[0][d] + lds_ctx[1][d] + lds_ctx[2][d] + lds_ctx[3][d];
  if (threadIdx.x == 0) {
    ws_ms[((size_t)b*16 + chunk)*2]     = M;
    ws_ms[((size_t)b*16 + chunk)*2 + 1] = ssum_c;
  }
}

// K2: combine 16 chunk-partials per b; build transposed rnn input + hidden.
__global__ __launch_bounds__(256) void k_combine(const float* __restrict__ ws_ms,
                                                 const float* __restrict__ ws_ctx,
                                                 const float* __restrict__ hidden,
                                                 const float* __restrict__ emb_table,
                                                 const int* __restrict__ x,
                                                 float* __restrict__ ws_rnnT,
                                                 float* __restrict__ ws_hidT) {
  const int b = blockIdx.x;
  float mc[16], sc[16];
#pragma unroll
  for (int c = 0; c < 16; ++c) {
    mc[c] = ws_ms[(b*16 + c)*2];
    sc[c] = ws_ms[(b*16 + c)*2 + 1];
  }
  float M = mc[0];
#pragma unroll
  for (int c = 1; c < 16; ++c) M = fmaxf(M, mc[c]);
  float wc[16], Ssum = 0.f;
#pragma unroll
  for (int c = 0; c < 16; ++c) { wc[c] = __expf(mc[c] - M); Ssum += wc[c]*sc[c]; }
  const float inv = 1.f / Ssum;
  for (int d = threadIdx.x; d < TWOH; d += 256) {
    float a = 0.f;
#pragma unroll
    for (int c = 0; c < 16; ++c) a += wc[c] * ws_ctx[((size_t)b*16 + c)*TWOH + d];
    ws_rnnT[(size_t)d*64 + b] = a * inv;
  }
  const int xb = x[b];
  for (int e = threadIdx.x; e < EMB; e += 256)
    ws_rnnT[(size_t)(TWOH + e)*64 + b] = emb_table[(size_t)xb*EMB + e];
  for (int k = threadIdx.x; k < HDIM; k += 256)
    ws_hidT[(size_t)k*64 + b] = hidden[b*HDIM + k];
}

// K3: gate partials. Split-K=4 (896 k each, 7 chunks of 128).
__global__ __launch_bounds__(256) void k_gates(const float* __restrict__ ws_rnnT,
                                               const float* __restrict__ ws_hidT,
                                               const float* __restrict__ W_ih,
                                               const float* __restrict__ W_hh,
                                               float* __restrict__ ws_gp) {
  __shared__ float  lds_h[128*64];   // 32 KB
  __shared__ float4 lds_w[32*32];    // 16 KB  [row][k/4]
  const int lane = threadIdx.x & 63;
  const int wave = threadIdx.x >> 6;
  const int part = blockIdx.x >> 7;    // 0..3
  const int rg   = blockIdx.x & 127;   // 0..127
  const int j0   = rg * 32;
  const int r0   = wave * 8;

  float acc[8];
#pragma unroll
  for (int r = 0; r < 8; ++r) acc[r] = 0.f;

  for (int c = 0; c < 7; ++c) {
    const int kg = part*896 + c*128;
    const float* hsrc = (kg < KDIM) ? (ws_rnnT + (size_t)kg*64)
                                    : (ws_hidT + (size_t)(kg - KDIM)*64);
    const float4* s4 = reinterpret_cast<const float4*>(hsrc);
    float4* l4 = reinterpret_cast<float4*>(lds_h);
    for (int i = threadIdx.x; i < 2048; i += 256) l4[i] = s4[i];
    for (int i = threadIdx.x; i < 1024; i += 256) {
      const int r = i >> 5, cc = i & 31;
      const int j = j0 + r;
      const float* wrow = (kg < KDIM) ? (W_ih + (size_t)j*KDIM + kg)
                                      : (W_hh + (size_t)j*HDIM + (kg - KDIM));
      lds_w[i] = *reinterpret_cast<const float4*>(wrow + cc*4);
    }
    __syncthreads();
    for (int kk = 0; kk < 128; kk += 4) {
      const float v0 = lds_h[(kk+0)*64 + lane];
      const float v1 = lds_h[(kk+1)*64 + lane];
      const float v2 = lds_h[(kk+2)*64 + lane];
      const float v3 = lds_h[(kk+3)*64 + lane];
      const int wbase = r0*32 + (kk >> 2);
#pragma unroll
      for (int r = 0; r < 8; ++r) {
        const float4 wv = lds_w[wbase + r*32];
        acc[r] = fmaf(v0, wv.x, acc[r]);
        acc[r] = fmaf(v1, wv.y, acc[r]);
        acc[r] = fmaf(v2, wv.z, acc[r]);
        acc[r] = fmaf(v3, wv.w, acc[r]);
      }
    }
    __syncthreads();
  }
#pragma unroll
  for (int r = 0; r < 8; ++r)
    ws_gp[((size_t)part*4096 + j0 + r0 + r)*64 + lane] = acc[r];
}

// K3b: sum 4 partials + biases, LSTM pointwise.
__global__ __launch_bounds__(256) void k_lstm(const float* __restrict__ ws_gp,
                                              const float* __restrict__ b_ih,
                                              const float* __restrict__ b_hh,
                                              const float* __restrict__ cell,
                                              float* __restrict__ out_h,
                                              float* __restrict__ out_c,
                                              float* __restrict__ ws_hT) {
  const int id = blockIdx.x*256 + threadIdx.x;  // 65536
  const int h = id >> 6, b = id & 63;
  float g[4];
#pragma unroll
  for (int gg = 0; gg < 4; ++gg) {
    const int j = gg*1024 + h;
    float v = b_ih[j] + b_hh[j];
#pragma unroll
    for (int p = 0; p < 4; ++p) v += ws_gp[((size_t)p*4096 + j)*64 + b];
    g[gg] = v;
  }
  const float iv = sigmoidf_(g[0]);
  const float fv = sigmoidf_(g[1]);
  const float gv = tanhf(g[2]);
  const float ov = sigmoidf_(g[3]);
  const float cold = cell[b*HDIM + h];
  const float cn = fmaf(fv, cold, iv*gv);
  const float hn = ov * tanhf(cn);
  out_h[b*HDIM + h] = hn;
  out_c[b*HDIM + h] = cn;
  ws_hT[(size_t)h*64 + b] = hn;
}

// K4 v4: block = 64 output rows, wave = 16 rows, lanes = b. 500 blocks.
// 20 LDS instrs per 64 FMAs (was 12 per 32).
__global__ __launch_bounds__(256) void k_fc(const float* __restrict__ ws_hT,
                                            const float* __restrict__ fc_W,
                                            const float* __restrict__ fc_b,
                                            float* __restrict__ preds) {
  __shared__ float  lds_h[128*64];   // 32 KB
  __shared__ float4 lds_w[64*32];    // 32 KB  [row][k/4]
  const int lane = threadIdx.x & 63;
  const int wave = threadIdx.x >> 6;
  const int ob = blockIdx.x * 64;
  const int r0 = wave * 16;

  float acc[16];
#pragma unroll
  for (int r = 0; r < 16; ++r) acc[r] = 0.f;

  for (int c = 0; c < 8; ++c) {
    const int k0 = c*128;
    const float4* s4 = reinterpret_cast<const float4*>(ws_hT + (size_t)k0*64);
    float4* l4 = reinterpret_cast<float4*>(lds_h);
    for (int i = threadIdx.x; i < 2048; i += 256) l4[i] = s4[i];
    for (int i = threadIdx.x; i < 2048; i += 256) {
      const int r = i >> 5, cc = i & 31;
      lds_w[i] = *reinterpret_cast<const float4*>(fc_W + (size_t)(ob + r)*HDIM + k0 + cc*4);
    }
    __syncthreads();
    for (int kk = 0; kk < 128; kk += 4) {
      const float v0 = lds_h[(kk+0)*64 + lane];
      const float v1 = lds_h[(kk+1)*64 + lane];
      const float v2 = lds_h[(kk+2)*64 + lane];
      const float v3 = lds_h[(kk+3)*64 + lane];
      const int wbase = r0*32 + (kk >> 2);
#pragma unroll
      for (int r = 0; r < 16; ++r) {
        const float4 wv = lds_w[wbase + r*32];
        acc[r] = fmaf(v0, wv.x, acc[r]);
        acc[r] = fmaf(v1, wv.y, acc[r]);
        acc[r] = fmaf(v2, wv.z, acc[r]);
        acc[r] = fmaf(v3, wv.w, acc[r]);
      }
    }
    __syncthreads();
  }

  const int orow = ob + r0;
  float* p = preds + (size_t)lane*VOUT + orow;
#pragma unroll
  for (int r4 = 0; r4 < 16; r4 += 4) {
    float4 st = make_float4(acc[r4]   + fc_b[orow + r4],
                            acc[r4+1] + fc_b[orow + r4+1],
                            acc[r4+2] + fc_b[orow + r4+2],
                            acc[r4+3] + fc_b[orow + r4+3]);
    *reinterpret_cast<float4*>(p + r4) = st;
  }
}

extern "C" void kernel_launch(void* const* d_in, const int* in_sizes, int n_in,
                              void* d_out, int out_size, void* d_ws, size_t ws_size,
                              hipStream_t stream) {
  const int*   x      = (const int*)  d_in[0];
  const float* enc    = (const float*)d_in[1];
  const float* hidden = (const float*)d_in[2];
  const float* cell   = (const float*)d_in[3];
  const float* embt   = (const float*)d_in[4];
  const float* eW     = (const float*)d_in[5];
  const float* eb     = (const float*)d_in[6];
  const float* W_ih   = (const float*)d_in[7];
  const float* W_hh   = (const float*)d_in[8];
  const float* b_ih   = (const float*)d_in[9];
  const float* b_hh   = (const float*)d_in[10];
  const float* fc_W   = (const float*)d_in[11];
  const float* fc_b   = (const float*)d_in[12];

  float* out   = (float*)d_out;
  float* preds = out;                              // 64*32000
  float* out_h = out + (size_t)BATCH*VOUT;         // 64*1024
  float* out_c = out_h + BATCH*HDIM;               // 64*1024
  float* ws    = (float*)d_ws;

  k_attn<<<dim3(16, 64), 256, 0, stream>>>(enc, eW, eb, hidden, ws + WS_MS, ws + WS_CTX);
  k_combine<<<64, 256, 0, stream>>>(ws + WS_MS, ws + WS_CTX, hidden, embt, x,
                                    ws + WS_RNNT, ws + WS_HIDT);
  k_gates<<<512, 256, 0, stream>>>(ws + WS_RNNT, ws + WS_HIDT, W_ih, W_hh, ws + WS_GP);
  k_lstm<<<256, 256, 0, stream>>>(ws + WS_GP, b_ih, b_hh, cell, out_h, out_c, ws + WS_HT);
  k_fc<<<500, 256, 0, stream>>>(ws + WS_HT, fc_W, fc_b, preds);
}